// Round 6
// baseline (249.633 us; speedup 1.0000x reference)
//
#include <hip/hip_runtime.h>

// NTN: out[n,k] = relu( cos(x1 @ W1[k], x2 @ W2[k]) + [x1,x2]·V[k] + b[k] )
// N=32768, D=128, K=16.
// R6 = R3 proven per-wave shape (nt=2, ~110 VGPR, no spill) + 16KB chunks:
//  - LDS 2 x 16KB = 32KB/block -> 4 blocks/CU (16 waves/CU, 2x R3's TLP).
//    Latency-bound diagnosis: R3 had MfmaUtil 28% with LDS floor ~8us and
//    MFMA floor ~17us -- pipes half-idle; more independent blocks per CU
//    overlap each other's barrier drains (m114).
//  - chunk cc = k*4 + q4 (16KB): both sides, e-quarter q4 (2 e-tiles of 16).
//    16 chunks per block (k-range 4), ping-pong, 16 barriers (same as R3).
//  - grid 1024 = (rb 0..255 : 128 rows) x (kh 0..3); launch_bounds(256,4).
//  - prep: coalesced LDS-transpose swizzle (R5), V folded into same launch.

typedef __attribute__((ext_vector_type(8))) __bf16 bf16x8;
typedef __attribute__((ext_vector_type(8))) unsigned short us8;
typedef __attribute__((ext_vector_type(4))) float f32x4;

static __device__ __forceinline__ unsigned short f2bf(float f) {
  unsigned u = __float_as_uint(f);
  u += 0x7FFFu + ((u >> 16) & 1u);   // round-to-nearest-even
  return (unsigned short)(u >> 16);
}

static __device__ __forceinline__ bf16x8 as_bf(us8 u) {
  bf16x8 r;
  __builtin_memcpy(&r, &u, sizeof(r));
  return r;
}

// ---------------- prep: coalesced transpose-swizzle ----------------
// wsW: 64 chunks (cc = k*4 + q4) of 1024 16B-units (16KB).
//   unit-in-chunk: side*512 + et2*256 + s*64 + lane  (et2 = e-tile within quarter)
//   frag[j] = W_side[k][d = s*32 + (lane>>4)*8 + j][e = q4*32 + et2*16 + (lane&15)]
// wsV: unit cs*64+lane: frag[j] = V[lane&15][c = cs*32 + (lane>>4)*8 + j]
// Grid: 65 blocks. Blocks 0..63: (k = b>>2, side = (b>>1)&1, h = b&1) covering
// e in [h*64, h*64+64) = quarters 2h, 2h+1. Block 64: V.
__global__ void ntn_prep(const float* __restrict__ W1, const float* __restrict__ W2,
                         const float* __restrict__ V,
                         unsigned short* __restrict__ wsW, unsigned short* __restrict__ wsV) {
  const int t = threadIdx.x;
  const int blk = blockIdx.x;
  if (blk == 64) {   // V: 512 us8 units
    if (t < 128) {
#pragma unroll
      for (int ui = 0; ui < 4; ++ui) {
        int u = ui * 128 + t;
        int lane = u & 63, cs = u >> 6;
        int q = lane >> 4, l15 = lane & 15;
        const float* src = V + l15 * 256 + cs * 32 + q * 8;
        us8 r;
#pragma unroll
        for (int j = 0; j < 8; ++j) r[j] = f2bf(src[j]);
        *(us8*)(wsV + (size_t)u * 8) = r;
      }
    }
    return;
  }

  __shared__ float T[128 * 68];   // 64 cols used; stride 68 keeps col-reads cheap
  const int k = blk >> 2, side = (blk >> 1) & 1, h = blk & 1;
  const float* W = (side ? W2 : W1) + k * 16384 + h * 64;

  // load 128 d-rows x 64 e-cols, coalesced float4
#pragma unroll
  for (int i = 0; i < 8; ++i) {
    int fidx = i * 256 + t;          // 0..2047
    int d = fidx >> 4, c4 = fidx & 15;
    float4 v = *(const float4*)(W + d * 128 + c4 * 4);
    *(float4*)&T[d * 68 + c4 * 4] = v;
  }
  __syncthreads();

  // emit 1024 us8 units into chunks cc = k*4 + 2h + (et2f>>1)
#pragma unroll
  for (int ui = 0; ui < 4; ++ui) {
    int u = ui * 256 + t;            // 0..1023
    int lane = u & 63, s = (u >> 6) & 3, et2f = (u >> 8) & 3;
    int q = lane >> 4, l15 = lane & 15;
    int d0 = s * 32 + q * 8;
    int el = et2f * 16 + l15;        // e - h*64
    us8 r;
#pragma unroll
    for (int j = 0; j < 8; ++j) r[j] = f2bf(T[(d0 + j) * 68 + el]);
    int cc = k * 4 + h * 2 + (et2f >> 1);
    int uic = side * 512 + (et2f & 1) * 256 + s * 64 + lane;
    *(us8*)(wsW + ((size_t)cc * 1024 + uic) * 8) = r;
  }
}

// ---------------- main ----------------
__global__ __launch_bounds__(256, 4) void ntn_main(
    const float* __restrict__ x1, const float* __restrict__ x2,
    const float* __restrict__ b,
    const unsigned short* __restrict__ wsW, const unsigned short* __restrict__ wsV,
    float* __restrict__ out) {
  __shared__ uint4 ldsW[2][1024];   // two 16KB chunk slots = 32KB -> 4 blocks/CU

  const int tid = threadIdx.x;
  const int lane = tid & 63, wave = tid >> 6;
  const int q = lane >> 4, l15 = lane & 15;
  const int kh = blockIdx.x & 3;          // k range [4kh, 4kh+4)
  const int rb = blockIdx.x >> 2;         // 128-row group
  const int rowbase = rb * 128 + wave * 32;

  const f32x4 zero4 = {0.f, 0.f, 0.f, 0.f};

  // stage one 16KB chunk: 4 glds x (64 lanes x 16B) per wave
  auto stage = [&](int cc, int slot) {
    const unsigned short* src = wsW + (size_t)cc * 8192 + (size_t)(wave * 256 + lane) * 8;
    uint4* dst = &ldsW[slot][wave * 256];
#pragma unroll
    for (int i = 0; i < 4; ++i)
      __builtin_amdgcn_global_load_lds(
          (__attribute__((address_space(1))) void*)(void*)(src + i * 512),
          (__attribute__((address_space(3))) void*)(dst + i * 64), 16, 0, 0);
  };

  const int cbase = kh * 16;
  stage(cbase, 0);

  // ---- X fragments (B-operand): frag[j] = X[rowbase+nt*16+l15][d = s*32+q*8+j] ----
  bf16x8 xb[2][2][4];   // [side][nt][s] = 64 VGPRs
#pragma unroll
  for (int side = 0; side < 2; ++side) {
    const float* xp0 = side ? x2 : x1;
#pragma unroll
    for (int nt = 0; nt < 2; ++nt) {
#pragma unroll
      for (int s = 0; s < 4; ++s) {
        const float* p = xp0 + (size_t)(rowbase + nt * 16 + l15) * 128 + s * 32 + q * 8;
        float4 v0 = *(const float4*)p;
        float4 v1 = *(const float4*)(p + 4);
        us8 uu;
        uu[0] = f2bf(v0.x); uu[1] = f2bf(v0.y); uu[2] = f2bf(v0.z); uu[3] = f2bf(v0.w);
        uu[4] = f2bf(v1.x); uu[5] = f2bf(v1.y); uu[6] = f2bf(v1.z); uu[7] = f2bf(v1.w);
        xb[side][nt][s] = as_bf(uu);
      }
    }
  }

  // ---- part2 + b via MFMA (A = V frags: M=k; B = X frags) ----
  f32x4 accP[2];
  {
    float4 bv = *(const float4*)(b + q * 4);
#pragma unroll
    for (int nt = 0; nt < 2; ++nt) {
      f32x4 a = zero4;
#pragma unroll
      for (int cs = 0; cs < 8; ++cs) {
        bf16x8 vf = as_bf(*(const us8*)(wsV + (size_t)(cs * 64 + lane) * 8));
        a = __builtin_amdgcn_mfma_f32_16x16x32_bf16(vf, xb[cs >> 2][nt][cs & 3], a, 0, 0, 0);
      }
      a.x += bv.x; a.y += bv.y; a.z += bv.z; a.w += bv.w;
      accP[nt] = a;   // lane quad q holds part2+b for k = q*4 + reg
    }
  }

  float nm[2] = {0.f, 0.f}, q1[2] = {0.f, 0.f}, q2[2] = {0.f, 0.f};

  // one 16KB chunk (2 e-tiles, both sides): fold into nm/q1/q2
  auto compute = [&](int slot) {
#pragma unroll
    for (int et = 0; et < 2; ++et) {
      bf16x8 wa[4], wb[4];
#pragma unroll
      for (int s = 0; s < 4; ++s) {
        wa[s] = as_bf(*(const us8*)&ldsW[slot][et * 256 + s * 64 + lane]);
        wb[s] = as_bf(*(const us8*)&ldsW[slot][512 + et * 256 + s * 64 + lane]);
      }
#pragma unroll
      for (int nt = 0; nt < 2; ++nt) {
        f32x4 a1 = zero4, a2 = zero4;
#pragma unroll
        for (int s = 0; s < 4; ++s)
          a1 = __builtin_amdgcn_mfma_f32_16x16x32_bf16(wa[s], xb[0][nt][s], a1, 0, 0, 0);
#pragma unroll
        for (int s = 0; s < 4; ++s)
          a2 = __builtin_amdgcn_mfma_f32_16x16x32_bf16(wb[s], xb[1][nt][s], a2, 0, 0, 0);
        nm[nt] += a1.x * a2.x + a1.y * a2.y + a1.z * a2.z + a1.w * a2.w;
        q1[nt] += a1.x * a1.x + a1.y * a1.y + a1.z * a1.z + a1.w * a1.w;
        q2[nt] += a2.x * a2.x + a2.y * a2.y + a2.z * a2.z + a2.w * a2.w;
      }
    }
  };

#pragma unroll 1
  for (int kk = 0; kk < 4; ++kk) {
#pragma unroll
    for (int q4 = 0; q4 < 4; ++q4) {
      const int c = kk * 4 + q4;           // 0..15
      __syncthreads();                     // chunk c arrived in slot c&1
      if (c < 15) stage(cbase + c + 1, (c + 1) & 1);
      compute(c & 1);
    }

    const int k = kh * 4 + kk;
#pragma unroll
    for (int nt = 0; nt < 2; ++nt) {
      float n = nm[nt], s1 = q1[nt], s2 = q2[nt];
      n  += __shfl_xor(n, 16);  n  += __shfl_xor(n, 32);
      s1 += __shfl_xor(s1, 16); s1 += __shfl_xor(s1, 32);
      s2 += __shfl_xor(s2, 16); s2 += __shfl_xor(s2, 32);
      float d1 = fmaxf(sqrtf(s1), 1e-8f);
      float d2 = fmaxf(sqrtf(s2), 1e-8f);
      float p1 = n / (d1 * d2);
      float pc = (kk == 0) ? accP[nt].x : (kk == 1) ? accP[nt].y
               : (kk == 2) ? accP[nt].z : accP[nt].w;
      if (q == kh)
        out[(size_t)(rowbase + nt * 16 + l15) * 16 + k] = fmaxf(p1 + pc, 0.f);
      nm[nt] = 0.f; q1[nt] = 0.f; q2[nt] = 0.f;
    }
  }
}

extern "C" void kernel_launch(void* const* d_in, const int* in_sizes, int n_in,
                              void* d_out, int out_size, void* d_ws, size_t ws_size,
                              hipStream_t stream) {
  const float* x1 = (const float*)d_in[0];
  const float* x2 = (const float*)d_in[1];
  const float* W1 = (const float*)d_in[2];
  const float* W2 = (const float*)d_in[3];
  const float* V  = (const float*)d_in[4];
  const float* b  = (const float*)d_in[5];
  float* out = (float*)d_out;
  unsigned short* wsW = (unsigned short*)d_ws;
  unsigned short* wsV = wsW + (size_t)65536 * 8;   // 1MB offset

  ntn_prep<<<65, 256, 0, stream>>>(W1, W2, V, wsW, wsV);
  ntn_main<<<1024, 256, 0, stream>>>(x1, x2, b, wsW, wsV, out);
}

// Round 7
// 128.136 us; speedup vs baseline: 1.9482x; 1.9482x over previous
//
#include <hip/hip_runtime.h>

// NTN: out[n,k] = relu( cos(x1 @ W1[k], x2 @ W2[k]) + [x1,x2]·V[k] + b[k] )
// N=32768, D=128, K=16.
// R7 = R6 with launch_bounds(256,2) [was (256,4) -> 64-reg budget -> 290MB spill].
// Occupancy comes from ACTUAL regs: body ~108 VGPR <= 128 -> 4 waves/SIMD;
// LDS 32KB/block -> 4 blocks/CU; grid 1024 = 4/CU -> 16 waves/CU (2x R3).
//  - chunk cc = k*4 + q4 (16KB): both sides, e-quarter q4 (2 e-tiles of 16).
//    16 chunks per block (k-range 4), ping-pong in 2x16KB LDS slots.
//  - X frags (nt=2, 64 VGPRs) in registers; products folded immediately into
//    nm/q1/q2; e-reduction = in-lane FMAs + shfl_xor(16)+shfl_xor(32).
//  - part2+b via MFMA with V A-frags, kept in f32x4 accP (static indexing only;
//    R4 showed dynamic indexing -> LDS-lowered arrays + bank conflicts).
//  - prep: coalesced LDS-transpose swizzle; V folded into same launch.

typedef __attribute__((ext_vector_type(8))) __bf16 bf16x8;
typedef __attribute__((ext_vector_type(8))) unsigned short us8;
typedef __attribute__((ext_vector_type(4))) float f32x4;

static __device__ __forceinline__ unsigned short f2bf(float f) {
  unsigned u = __float_as_uint(f);
  u += 0x7FFFu + ((u >> 16) & 1u);   // round-to-nearest-even
  return (unsigned short)(u >> 16);
}

static __device__ __forceinline__ bf16x8 as_bf(us8 u) {
  bf16x8 r;
  __builtin_memcpy(&r, &u, sizeof(r));
  return r;
}

// ---------------- prep: coalesced transpose-swizzle ----------------
// wsW: 64 chunks (cc = k*4 + q4) of 1024 16B-units (16KB).
//   unit-in-chunk: side*512 + et2*256 + s*64 + lane
//   frag[j] = W_side[k][d = s*32 + (lane>>4)*8 + j][e = q4*32 + et2*16 + (lane&15)]
// wsV: unit cs*64+lane: frag[j] = V[lane&15][c = cs*32 + (lane>>4)*8 + j]
__global__ void ntn_prep(const float* __restrict__ W1, const float* __restrict__ W2,
                         const float* __restrict__ V,
                         unsigned short* __restrict__ wsW, unsigned short* __restrict__ wsV) {
  const int t = threadIdx.x;
  const int blk = blockIdx.x;
  if (blk == 64) {   // V: 512 us8 units
    if (t < 128) {
#pragma unroll
      for (int ui = 0; ui < 4; ++ui) {
        int u = ui * 128 + t;
        int lane = u & 63, cs = u >> 6;
        int q = lane >> 4, l15 = lane & 15;
        const float* src = V + l15 * 256 + cs * 32 + q * 8;
        us8 r;
#pragma unroll
        for (int j = 0; j < 8; ++j) r[j] = f2bf(src[j]);
        *(us8*)(wsV + (size_t)u * 8) = r;
      }
    }
    return;
  }

  __shared__ float T[128 * 68];
  const int k = blk >> 2, side = (blk >> 1) & 1, h = blk & 1;
  const float* W = (side ? W2 : W1) + k * 16384 + h * 64;

  // load 128 d-rows x 64 e-cols, coalesced float4
#pragma unroll
  for (int i = 0; i < 8; ++i) {
    int fidx = i * 256 + t;          // 0..2047
    int d = fidx >> 4, c4 = fidx & 15;
    float4 v = *(const float4*)(W + d * 128 + c4 * 4);
    *(float4*)&T[d * 68 + c4 * 4] = v;
  }
  __syncthreads();

  // emit 1024 us8 units into chunks cc = k*4 + 2h + (et2f>>1)
#pragma unroll
  for (int ui = 0; ui < 4; ++ui) {
    int u = ui * 256 + t;            // 0..1023
    int lane = u & 63, s = (u >> 6) & 3, et2f = (u >> 8) & 3;
    int q = lane >> 4, l15 = lane & 15;
    int d0 = s * 32 + q * 8;
    int el = et2f * 16 + l15;        // e - h*64
    us8 r;
#pragma unroll
    for (int j = 0; j < 8; ++j) r[j] = f2bf(T[(d0 + j) * 68 + el]);
    int cc = k * 4 + h * 2 + (et2f >> 1);
    int uic = side * 512 + (et2f & 1) * 256 + s * 64 + lane;
    *(us8*)(wsW + ((size_t)cc * 1024 + uic) * 8) = r;
  }
}

// ---------------- main ----------------
__global__ __launch_bounds__(256, 2) void ntn_main(
    const float* __restrict__ x1, const float* __restrict__ x2,
    const float* __restrict__ b,
    const unsigned short* __restrict__ wsW, const unsigned short* __restrict__ wsV,
    float* __restrict__ out) {
  __shared__ uint4 ldsW[2][1024];   // two 16KB chunk slots = 32KB -> 4 blocks/CU

  const int tid = threadIdx.x;
  const int lane = tid & 63, wave = tid >> 6;
  const int q = lane >> 4, l15 = lane & 15;
  const int kh = blockIdx.x & 3;          // k range [4kh, 4kh+4)
  const int rb = blockIdx.x >> 2;         // 128-row group
  const int rowbase = rb * 128 + wave * 32;

  const f32x4 zero4 = {0.f, 0.f, 0.f, 0.f};

  // stage one 16KB chunk: 4 glds x (64 lanes x 16B) per wave
  auto stage = [&](int cc, int slot) {
    const unsigned short* src = wsW + (size_t)cc * 8192 + (size_t)(wave * 256 + lane) * 8;
    uint4* dst = &ldsW[slot][wave * 256];
#pragma unroll
    for (int i = 0; i < 4; ++i)
      __builtin_amdgcn_global_load_lds(
          (__attribute__((address_space(1))) void*)(void*)(src + i * 512),
          (__attribute__((address_space(3))) void*)(dst + i * 64), 16, 0, 0);
  };

  const int cbase = kh * 16;
  stage(cbase, 0);

  // ---- X fragments (B-operand): frag[j] = X[rowbase+nt*16+l15][d = s*32+q*8+j] ----
  bf16x8 xb[2][2][4];   // [side][nt][s] = 64 VGPRs
#pragma unroll
  for (int side = 0; side < 2; ++side) {
    const float* xp0 = side ? x2 : x1;
#pragma unroll
    for (int nt = 0; nt < 2; ++nt) {
#pragma unroll
      for (int s = 0; s < 4; ++s) {
        const float* p = xp0 + (size_t)(rowbase + nt * 16 + l15) * 128 + s * 32 + q * 8;
        float4 v0 = *(const float4*)p;
        float4 v1 = *(const float4*)(p + 4);
        us8 uu;
        uu[0] = f2bf(v0.x); uu[1] = f2bf(v0.y); uu[2] = f2bf(v0.z); uu[3] = f2bf(v0.w);
        uu[4] = f2bf(v1.x); uu[5] = f2bf(v1.y); uu[6] = f2bf(v1.z); uu[7] = f2bf(v1.w);
        xb[side][nt][s] = as_bf(uu);
      }
    }
  }

  // ---- part2 + b via MFMA (A = V frags: M=k; B = X frags) ----
  f32x4 accP[2];
  {
    float4 bv = *(const float4*)(b + q * 4);
#pragma unroll
    for (int nt = 0; nt < 2; ++nt) {
      f32x4 a = zero4;
#pragma unroll
      for (int cs = 0; cs < 8; ++cs) {
        bf16x8 vf = as_bf(*(const us8*)(wsV + (size_t)(cs * 64 + lane) * 8));
        a = __builtin_amdgcn_mfma_f32_16x16x32_bf16(vf, xb[cs >> 2][nt][cs & 3], a, 0, 0, 0);
      }
      a.x += bv.x; a.y += bv.y; a.z += bv.z; a.w += bv.w;
      accP[nt] = a;   // lane quad q holds part2+b for k = q*4 + reg
    }
  }

  float nm[2] = {0.f, 0.f}, q1[2] = {0.f, 0.f}, q2[2] = {0.f, 0.f};

  // one 16KB chunk (2 e-tiles, both sides): fold into nm/q1/q2
  auto compute = [&](int slot) {
#pragma unroll
    for (int et = 0; et < 2; ++et) {
      bf16x8 wa[4], wb[4];
#pragma unroll
      for (int s = 0; s < 4; ++s) {
        wa[s] = as_bf(*(const us8*)&ldsW[slot][et * 256 + s * 64 + lane]);
        wb[s] = as_bf(*(const us8*)&ldsW[slot][512 + et * 256 + s * 64 + lane]);
      }
#pragma unroll
      for (int nt = 0; nt < 2; ++nt) {
        f32x4 a1 = zero4, a2 = zero4;
#pragma unroll
        for (int s = 0; s < 4; ++s)
          a1 = __builtin_amdgcn_mfma_f32_16x16x32_bf16(wa[s], xb[0][nt][s], a1, 0, 0, 0);
#pragma unroll
        for (int s = 0; s < 4; ++s)
          a2 = __builtin_amdgcn_mfma_f32_16x16x32_bf16(wb[s], xb[1][nt][s], a2, 0, 0, 0);
        nm[nt] += a1.x * a2.x + a1.y * a2.y + a1.z * a2.z + a1.w * a2.w;
        q1[nt] += a1.x * a1.x + a1.y * a1.y + a1.z * a1.z + a1.w * a1.w;
        q2[nt] += a2.x * a2.x + a2.y * a2.y + a2.z * a2.z + a2.w * a2.w;
      }
    }
  };

#pragma unroll 1
  for (int kk = 0; kk < 4; ++kk) {
#pragma unroll
    for (int q4 = 0; q4 < 4; ++q4) {
      const int c = kk * 4 + q4;           // 0..15
      __syncthreads();                     // chunk c arrived in slot c&1
      if (c < 15) stage(cbase + c + 1, (c + 1) & 1);
      compute(c & 1);
    }

    const int k = kh * 4 + kk;
#pragma unroll
    for (int nt = 0; nt < 2; ++nt) {
      float n = nm[nt], s1 = q1[nt], s2 = q2[nt];
      n  += __shfl_xor(n, 16);  n  += __shfl_xor(n, 32);
      s1 += __shfl_xor(s1, 16); s1 += __shfl_xor(s1, 32);
      s2 += __shfl_xor(s2, 16); s2 += __shfl_xor(s2, 32);
      float d1 = fmaxf(sqrtf(s1), 1e-8f);
      float d2 = fmaxf(sqrtf(s2), 1e-8f);
      float p1 = n / (d1 * d2);
      float pc = (kk == 0) ? accP[nt].x : (kk == 1) ? accP[nt].y
               : (kk == 2) ? accP[nt].z : accP[nt].w;
      if (q == kh)
        out[(size_t)(rowbase + nt * 16 + l15) * 16 + k] = fmaxf(p1 + pc, 0.f);
      nm[nt] = 0.f; q1[nt] = 0.f; q2[nt] = 0.f;
    }
  }
}

extern "C" void kernel_launch(void* const* d_in, const int* in_sizes, int n_in,
                              void* d_out, int out_size, void* d_ws, size_t ws_size,
                              hipStream_t stream) {
  const float* x1 = (const float*)d_in[0];
  const float* x2 = (const float*)d_in[1];
  const float* W1 = (const float*)d_in[2];
  const float* W2 = (const float*)d_in[3];
  const float* V  = (const float*)d_in[4];
  const float* b  = (const float*)d_in[5];
  float* out = (float*)d_out;
  unsigned short* wsW = (unsigned short*)d_ws;
  unsigned short* wsV = wsW + (size_t)65536 * 8;   // 1MB offset

  ntn_prep<<<65, 256, 0, stream>>>(W1, W2, V, wsW, wsV);
  ntn_main<<<1024, 256, 0, stream>>>(x1, x2, b, wsW, wsV, out);
}